// Round 14
// baseline (324.254 us; speedup 1.0000x reference)
//
#include <hip/hip_runtime.h>
#include <hip/hip_bf16.h>
#include <math.h>

// ---------------------------------------------------------------------------
// TernaryLeNet5 forward.
// R13: cooperative launch FAILED under the harness (eager output all-zero ->
// hipLaunchCooperativeKernel incompatible with its capture path). Grid-sync
// is unavailable; fusion must be sync-free. Reverted to R12-exact except:
//   - tern_pass1+tern_pass2 -> ONE kernel (tern_onepass, 80 blocks): every
//     block redundantly reduces its whole tensor (identical loop order ->
//     bitwise-identical delta across blocks, deterministic), then quantizes
//     its 1/16 stripe + writes masked partials for alpha. Tensors are tiny
//     (L2-resident) so the 16x redundant read is ~6us; deletes one kernel
//     and one launch boundary.
// 4 launches: tern_onepass, conv12, conv3_mfma, fc.
// Cross-session drift ~15% on identical code — compare within-run only.
// Known: harness's ~40us ws-poison fill is inside dur_us (uncontrollable).
// ---------------------------------------------------------------------------

typedef __attribute__((ext_vector_type(8))) short bf16x8;
typedef __attribute__((ext_vector_type(4))) float f32x4;

// ---- ws layout (float offsets) --------------------------------------------
// pb: ps1[5][16] @80, pcnt[5][16] @160 (slots 0..79 unused now)
static const size_t OFF_PB    = 0;        // 240 f32
static const size_t OFF_W1B   = 256;      // [32][32] bf16 = 512 f32
static const size_t OFF_W2B   = 1056;     // [64][25][32] bf16 = 25600 f32
static const size_t OFF_W3B   = 26656;    // [128][1600] bf16  = 102400 f32
static const size_t OFF_FW1T  = 129056;   // [120][84] f32, +-1/0
static const size_t OFF_FW2T  = 139136;   // [84][10] f32, +-1/0
static const size_t OFF_P2B   = 139976;   // [1024][1600] bf16 = 819200 f32
static const size_t OFF_H3    = 959176;   // [1024][120] f32
// total ~4.3 MB

#define BPT 16   // blocks per tensor in ternarize

__device__ __forceinline__ ushort f2bf(float v) {   // RNE float->bf16 bits
    unsigned u = __float_as_uint(v);
    unsigned r = (u + 0x7FFFu + ((u >> 16) & 1u)) >> 16;
    return (ushort)r;
}
__device__ __forceinline__ float bf2f(ushort h) {
    return __uint_as_float((unsigned)h << 16);
}

// tanh via hw exp: 1 - 2e/(1+e), e = exp(-2|x|) in (0,1] -> no overflow.
__device__ __forceinline__ float tanh_fast(float x) {
    float e = __expf(-2.0f * fabsf(x));
    float r = 1.0f - 2.0f * e / (1.0f + e);
    return copysignf(r, x);
}

__device__ __forceinline__ void tensor_select(int tensor,
        const float* w1, const float* w2, const float* w3,
        const float* fw1, const float* fw2,
        const float*& src, int& O, int& K) {
    switch (tensor) {
        case 0: src = w1;  O = 32;  K = 25;   break;
        case 1: src = w2;  O = 64;  K = 800;  break;
        case 2: src = w3;  O = 120; K = 1600; break;
        case 3: src = fw1; O = 84;  K = 120;  break;
        default: src = fw2; O = 10; K = 84;   break;
    }
}

__device__ __forceinline__ float block_sum_256(float v, float* sbuf) {
    #pragma unroll
    for (int off = 32; off > 0; off >>= 1) v += __shfl_down(v, off);
    const int wid = threadIdx.x >> 6;
    if ((threadIdx.x & 63) == 0) sbuf[wid] = v;
    __syncthreads();
    return sbuf[0] + sbuf[1] + sbuf[2] + sbuf[3];
}

// alpha for `tensor` from partials (redundant per-thread compute)
__device__ __forceinline__ float alpha_of(const float* pb, int tensor) {
    float s1 = 0.f, c = 0.f;
    #pragma unroll
    for (int i = 0; i < BPT; ++i) {
        s1 += pb[80 + tensor * BPT + i];
        c  += pb[160 + tensor * BPT + i];
    }
    return s1 / fmaxf(c, 1.0f);
}

// ---------------------------------------------------------------------------
// tern_onepass: block = (tensor, stripe). Phase A: redundant full-tensor
// abs-sum (identical loop order in every block of a tensor -> bitwise-equal
// delta, deterministic). Phase B: quantize own stripe + masked partials.
__global__ __launch_bounds__(256)
void tern_onepass(const float* w1, const float* w2, const float* w3,
                  const float* fw1, const float* fw2,
                  ushort* w1b, ushort* w2b, ushort* w3b,
                  float* fw1t, float* fw2t, float* pb) {
    __shared__ float sbuf[4];
    const int tensor = blockIdx.x / BPT;
    const int blk    = blockIdx.x % BPT;
    const float* src; int O, K;
    tensor_select(tensor, w1, w2, w3, fw1, fw2, src, O, K);
    const int n = O * K;

    // Phase A: full-tensor reduction, same iteration pattern in all blocks.
    float s = 0.f;
    for (int i = threadIdx.x; i < n; i += 256) s += fabsf(src[i]);
    s = block_sum_256(s, sbuf);
    const float delta = 0.7f * s / (float)n;
    __syncthreads();   // protect sbuf before reuse

    const ushort BP = 0x3F80u, BN = 0xBF80u;   // bf16 +1, -1
    float s1 = 0.f, cnt = 0.f;

    if (tensor == 0) {
        // w1 -> bf16 [oc][32]: k 0..24 = taps, k 25..31 = 0 (pads MFMA K)
        for (int j = blk * 256 + threadIdx.x; j < 1024; j += BPT * 256) {
            const int oc = j >> 5, kk = j & 31;
            ushort qb = 0;
            if (kk < 25) {
                float w = src[oc * 25 + kk];
                float aw = fabsf(w);
                if (aw > delta) { s1 += aw; cnt += 1.f; qb = (w > 0.f) ? BP : BN; }
            }
            w1b[j] = qb;
        }
    } else if (tensor == 2) {
        // w3 -> bf16 [oc][1600] row-linear; zero-fill pad rows 120..127
        for (int i = blk * 256 + threadIdx.x; i < 128 * 1600; i += BPT * 256) {
            ushort qb = 0;
            if (i < n) {
                float w = src[i];
                float aw = fabsf(w);
                if (aw > delta) { s1 += aw; cnt += 1.f; qb = (w > 0.f) ? BP : BN; }
            }
            w3b[i] = qb;
        }
    } else if (tensor == 1) {
        // w2 -> bf16 [oc][tap][ic]; src is [oc][ic][kh][kw]
        for (int i = blk * 256 + threadIdx.x; i < n; i += BPT * 256) {
            float w = src[i];
            float aw = fabsf(w);
            ushort qb = 0;
            if (aw > delta) { s1 += aw; cnt += 1.f; qb = (w > 0.f) ? BP : BN; }
            int oc = i / 800;
            int r  = i - oc * 800;
            int ic = r / 25;
            int tap = r - ic * 25;
            w2b[oc * 800 + tap * 32 + ic] = qb;
        }
    } else {
        float* dst = (tensor == 3) ? fw1t : fw2t;
        for (int i = blk * 256 + threadIdx.x; i < n; i += BPT * 256) {
            float w = src[i];
            float aw = fabsf(w);
            float q = 0.f;
            if (aw > delta) { s1 += aw; cnt += 1.f; q = (w > 0.f) ? 1.f : -1.f; }
            int o = i / K;
            int k = i - o * K;
            dst[k * O + o] = q;      // transpose to [k][O]
        }
    }
    __syncthreads();
    s1 = block_sum_256(s1, sbuf);
    __syncthreads();
    cnt = block_sum_256(cnt, sbuf);
    if (threadIdx.x == 0) {
        pb[80 + tensor * BPT + blk]  = s1;
        pb[160 + tensor * BPT + blk] = cnt;
    }
}

// ---------------------------------------------------------------------------
// conv2 MFMA inner (stride 40 sxt)
template<int TBASE, int TCNT>
__device__ __forceinline__ void conv2_phase(
        const ushort* __restrict__ w2b, const ushort* sxt,
        int n0, int mt0, int lane, f32x4 acc[4][2]) {
    const int col = lane & 15, quad = lane >> 4;
    bf16x8 bfr[TCNT][2];
    #pragma unroll
    for (int i = 0; i < TCNT; ++i) {
        const int tap = TBASE + i;
        #pragma unroll
        for (int np = 0; np < 2; ++np) {
            const int oc = n0 + np * 16 + col;
            bfr[i][np] = *(const bf16x8*)(w2b + (oc * 25 + tap) * 32 + quad * 8);
        }
    }
    #pragma unroll
    for (int mi = 0; mi < 4; ++mi) {
        int m = (mt0 + mi) * 16 + col;
        m = m < 100 ? m : 99;                     // clamp padding rows
        const int oh = m / 10, ow = m - oh * 10;
        const ushort* abase = sxt + (oh * 14 + ow) * 40 + quad * 8;
        #pragma unroll
        for (int i = 0; i < TCNT; ++i) {
            const int tap = TBASE + i;
            const int kh = tap / 5, kw = tap - kh * 5;
            bf16x8 af = *(const bf16x8*)(abase + (kh * 14 + kw) * 40);
            acc[mi][0] = __builtin_amdgcn_mfma_f32_16x16x32_bf16(af, bfr[i][0], acc[mi][0], 0, 0, 0);
            acc[mi][1] = __builtin_amdgcn_mfma_f32_16x16x32_bf16(af, bfr[i][1], acc[mi][1], 0, 0, 0);
        }
    }
}

// ---------------------------------------------------------------------------
// conv12 (R12-exact): conv1 MFMA (4-chunk im2col, stride-36 A) + pool +
// conv2 MFMA + pool. One image per block, 4 blocks/CU.
__global__ __launch_bounds__(256)
void conv12_kernel(const float* __restrict__ x, const ushort* __restrict__ w1b,
                   const float* __restrict__ b1, const ushort* __restrict__ w2b,
                   const float* __restrict__ b2, const float* __restrict__ pb,
                   ushort* __restrict__ p2b) {
    __shared__ __align__(16) char smem[40776];
    ushort* A      = (ushort*)smem;
    ushort* sxt    = (ushort*)smem;
    ushort* hb1    = (ushort*)(smem + 15680);
    float*  hb2    = (float*) (smem + 15680);
    ushort* sxb    = (ushort*)(smem + 38720);
    float*  salpha = (float*) (smem + 40768);

    const int n = blockIdx.x;
    const int t = threadIdx.x;
    const int wave = t >> 6, lane = t & 63;
    const int col = lane & 15, quad = lane >> 4;

    bf16x8 B0 = *(const bf16x8*)(w1b + col * 32 + quad * 8);
    bf16x8 B1 = *(const bf16x8*)(w1b + (col + 16) * 32 + quad * 8);
    const float b1reg = b1[t & 31];

    {   // stage x -> bf16 sxb
        float4 v = ((const float4*)(x + (size_t)n * 1024))[t];
        ushort4 q;
        q.x = f2bf(v.x); q.y = f2bf(v.y); q.z = f2bf(v.z); q.w = f2bf(v.w);
        *(ushort4*)(sxb + t * 4) = q;
        if (t == 0) salpha[0] = alpha_of(pb, 0);
        if (t == 1) salpha[1] = alpha_of(pb, 1);
    }
    __syncthreads();

    // ---- conv1: 4 chunks of tiles {13,13,13,10} -------------------------
    #pragma unroll
    for (int c = 0; c < 4; ++c) {
        const int tbase = c * 13;
        const int ct    = (c == 3) ? 10 : 13;
        const int pbase = tbase * 16;
        const int rows  = ct * 16;

        for (int r = t; r < rows; r += 256) {
            const int p = pbase + r;
            const int oh = p / 28, ow = p % 28;
            ushort v[25];
            #pragma unroll
            for (int kh = 0; kh < 5; ++kh) {
                const ushort* rr = sxb + (oh + kh) * 32 + ow;
                v[kh*5+0]=rr[0]; v[kh*5+1]=rr[1]; v[kh*5+2]=rr[2];
                v[kh*5+3]=rr[3]; v[kh*5+4]=rr[4];
            }
            uint2* arow = (uint2*)(A + r * 36);   // 72B rows: banks 18r%32
            #pragma unroll
            for (int j = 0; j < 6; ++j) {
                uint2 w;
                w.x = (unsigned)v[4*j]   | ((unsigned)v[4*j+1] << 16);
                w.y = (unsigned)v[4*j+2] | ((unsigned)v[4*j+3] << 16);
                arow[j] = w;
            }
            uint2 w6; w6.x = (unsigned)v[24]; w6.y = 0u;
            arow[6] = w6;
            uint2 w7; w7.x = 0u; w7.y = 0u;
            arow[7] = w7;
        }
        __syncthreads();

        for (int tl = wave; tl < ct; tl += 4) {
            const ushort* ap = A + (tl * 16 + col) * 36 + quad * 8;
            ushort4 lo = *(const ushort4*)ap;
            ushort4 hi = *(const ushort4*)(ap + 4);
            bf16x8 af;
            af[0]=(short)lo.x; af[1]=(short)lo.y; af[2]=(short)lo.z; af[3]=(short)lo.w;
            af[4]=(short)hi.x; af[5]=(short)hi.y; af[6]=(short)hi.z; af[7]=(short)hi.w;
            f32x4 z = {};
            f32x4 c0 = __builtin_amdgcn_mfma_f32_16x16x32_bf16(af, B0, z, 0, 0, 0);
            f32x4 c1 = __builtin_amdgcn_mfma_f32_16x16x32_bf16(af, B1, z, 0, 0, 0);
            const int p = pbase + tl * 16 + quad * 4;
            const int oh = p / 28, ow2 = (p % 28) >> 1;
            const int pos = oh * 14 + ow2;
            hb1[pos * 32 + col]            = f2bf(fmaxf(c0[0], c0[1]));
            hb1[(pos + 1) * 32 + col]      = f2bf(fmaxf(c0[2], c0[3]));
            hb1[pos * 32 + col + 16]       = f2bf(fmaxf(c1[0], c1[1]));
            hb1[(pos + 1) * 32 + col + 16] = f2bf(fmaxf(c1[2], c1[3]));
        }
        __syncthreads();
    }

    // ---- vertical pool + alpha/bias + tanh -> sxt (overlays A) ----------
    {
        const float a1 = salpha[0];
        const int oc = t & 31;
        for (int idx = t; idx < 6272; idx += 256) {
            const int pos2 = idx >> 5;
            const int ph = pos2 / 14, pw = pos2 - ph * 14;
            const int in0 = (2 * ph) * 14 + pw;
            float m = fmaxf(bf2f(hb1[in0 * 32 + oc]),
                            bf2f(hb1[(in0 + 14) * 32 + oc]));
            sxt[pos2 * 40 + oc] = f2bf(tanh_fast(fmaf(a1, m, b1reg)));
        }
    }
    __syncthreads();

    // ---- conv2 MFMA -----------------------------------------------------
    const int n0  = (wave & 1) * 32;
    const int mt0 = (wave >> 1) * 4;
    f32x4 acc2[4][2] = {};
    conv2_phase<0, 13>(w2b, sxt, n0, mt0, lane, acc2);
    conv2_phase<13, 12>(w2b, sxt, n0, mt0, lane, acc2);

    {   // horizontal pool in-register -> hb2[oc][50]
        #pragma unroll
        for (int mi = 0; mi < 4; ++mi) {
            const int mrow = (mt0 + mi) * 16 + quad * 4;
            if (mrow < 100) {
                #pragma unroll
                for (int np = 0; np < 2; ++np) {
                    const int oc = n0 + np * 16 + col;
                    float2 hm;
                    hm.x = fmaxf(acc2[mi][np][0], acc2[mi][np][1]);
                    hm.y = fmaxf(acc2[mi][np][2], acc2[mi][np][3]);
                    *(float2*)(&hb2[oc * 50 + (mrow >> 1)]) = hm;
                }
            }
        }
    }
    __syncthreads();

    const float a2 = salpha[1];
    for (int idx = t; idx < 1600; idx += 256) {
        const int oc = idx / 25, r = idx - oc * 25;
        const int ph = r / 5, pw = r - ph * 5;
        const float* hb = &hb2[oc * 50 + ph * 10 + pw];
        float m = fmaxf(hb[0], hb[5]);
        p2b[(size_t)n * 1600 + idx] = f2bf(tanh_fast(fmaf(a2, m, b2[oc])));
    }
}

// ---------------------------------------------------------------------------
// conv3 as MFMA GEMM: h3[1024][120] = tanh(a3*(P2 x W3^T) + b3)
template<int STEPS>
__device__ __forceinline__ void conv3_chunk(const ushort* Abase, const ushort* B0,
                                            const ushort* B1, f32x4& acc0, f32x4& acc1) {
    #pragma unroll
    for (int s = 0; s < STEPS; ++s) {
        bf16x8 af = *(const bf16x8*)(Abase + s * 32);
        bf16x8 b0 = *(const bf16x8*)(B0 + s * 32);
        bf16x8 b1 = *(const bf16x8*)(B1 + s * 32);
        acc0 = __builtin_amdgcn_mfma_f32_16x16x32_bf16(af, b0, acc0, 0, 0, 0);
        acc1 = __builtin_amdgcn_mfma_f32_16x16x32_bf16(af, b1, acc1, 0, 0, 0);
    }
}

__global__ __launch_bounds__(256)
void conv3_mfma(const ushort* __restrict__ p2b, const ushort* __restrict__ w3b,
                const float* __restrict__ b3, const float* __restrict__ pb,
                float* __restrict__ h3) {
    __shared__ float red[4][64][8];   // [wave][lane][np*4+reg]
    __shared__ float salpha;
    const int t = threadIdx.x;
    const int wave = t >> 6, lane = t & 63;
    const int mt = blockIdx.x >> 2;       // 0..63
    const int npair = blockIdx.x & 3;     // 0..3
    const int col = lane & 15, quad = lane >> 4;
    const int kstart = (wave < 2) ? wave * 13 : 26 + (wave - 2) * 12;  // 0,13,26,38

    if (t == 0) salpha = alpha_of(pb, 2);

    const ushort* Abase = p2b + (size_t)(mt * 16 + col) * 1600 + kstart * 32 + quad * 8;
    const ushort* B0 = w3b + (size_t)(npair * 32 + col) * 1600 + kstart * 32 + quad * 8;
    const ushort* B1 = B0 + 16 * 1600;

    f32x4 acc0 = {}, acc1 = {};
    if (wave < 2) conv3_chunk<13>(Abase, B0, B1, acc0, acc1);
    else          conv3_chunk<12>(Abase, B0, B1, acc0, acc1);

    #pragma unroll
    for (int r = 0; r < 4; ++r) {
        red[wave][lane][r]     = acc0[r];
        red[wave][lane][4 + r] = acc1[r];
    }
    __syncthreads();

    {   // thread t: lane l = t&63, reg vh = t>>6; handles np = 0 and 1
        const float a3 = salpha;
        const int l = t & 63, vh = t >> 6;
        const int lcol = l & 15, lquad = l >> 4;
        const int img = mt * 16 + lquad * 4 + vh;
        #pragma unroll
        for (int j = 0; j < 2; ++j) {
            const int v = j * 4 + vh;
            float s = red[0][l][v] + red[1][l][v] + red[2][l][v] + red[3][l][v];
            const int oc = npair * 32 + j * 16 + lcol;
            if (oc < 120) h3[(size_t)img * 120 + oc] = tanh_fast(fmaf(a3, s, b3[oc]));
        }
    }
}

// ---------------------------------------------------------------------------
// fc1 + tanh + fc2 + softmax. Block per image; alpha folded.
__global__ __launch_bounds__(128)
void fc_kernel(const float* __restrict__ h3, const float* __restrict__ fw1t,
               const float* __restrict__ fb1, const float* __restrict__ fw2t,
               const float* __restrict__ fb2, const float* __restrict__ pb,
               float* __restrict__ out) {
    const int n = blockIdx.x;
    __shared__ float sh[120];
    __shared__ float sh4[84];
    __shared__ float sl[10];
    __shared__ float salpha[2];
    const int t = threadIdx.x;
    if (t < 120) sh[t] = h3[(size_t)n * 120 + t];
    if (t == 120) salpha[0] = alpha_of(pb, 3);
    if (t == 121) salpha[1] = alpha_of(pb, 4);
    __syncthreads();
    if (t < 84) {
        const float af1 = salpha[0];
        float a = 0.f;
        #pragma unroll 4
        for (int k = 0; k < 120; ++k) a = fmaf(fw1t[k * 84 + t], sh[k], a);
        sh4[t] = tanh_fast(fmaf(af1, a, fb1[t]));
    }
    __syncthreads();
    if (t < 10) {
        const float af2 = salpha[1];
        float a = 0.f;
        #pragma unroll 4
        for (int k = 0; k < 84; ++k) a = fmaf(fw2t[k * 10 + t], sh4[k], a);
        const float lg = fmaf(af2, a, fb2[t]);
        sl[t] = lg;
        out[(size_t)n * 10 + t] = lg;
    }
    __syncthreads();
    if (t < 10) {
        float m = -INFINITY;
        #pragma unroll
        for (int i = 0; i < 10; ++i) m = fmaxf(m, sl[i]);
        float s = 0.f;
        #pragma unroll
        for (int i = 0; i < 10; ++i) s += expf(sl[i] - m);
        out[10240 + (size_t)n * 10 + t] = expf(sl[t] - m) / s;
    }
}

// ---------------------------------------------------------------------------
extern "C" void kernel_launch(void* const* d_in, const int* in_sizes, int n_in,
                              void* d_out, int out_size, void* d_ws, size_t ws_size,
                              hipStream_t stream) {
    const float* x   = (const float*)d_in[0];
    const float* w1  = (const float*)d_in[1];
    const float* b1  = (const float*)d_in[2];
    const float* w2  = (const float*)d_in[3];
    const float* b2  = (const float*)d_in[4];
    const float* w3  = (const float*)d_in[5];
    const float* b3  = (const float*)d_in[6];
    const float* fw1 = (const float*)d_in[7];
    const float* fb1 = (const float*)d_in[8];
    const float* fw2 = (const float*)d_in[9];
    const float* fb2 = (const float*)d_in[10];

    float* ws = (float*)d_ws;
    float*  pb   = ws + OFF_PB;
    ushort* w1b  = (ushort*)(ws + OFF_W1B);
    ushort* w2b  = (ushort*)(ws + OFF_W2B);
    ushort* w3b  = (ushort*)(ws + OFF_W3B);
    float*  fw1t = ws + OFF_FW1T;
    float*  fw2t = ws + OFF_FW2T;
    ushort* p2b  = (ushort*)(ws + OFF_P2B);
    float*  h3   = ws + OFF_H3;
    float*  out  = (float*)d_out;

    tern_onepass<<<5 * BPT, 256, 0, stream>>>(w1, w2, w3, fw1, fw2,
                                              w1b, w2b, w3b, fw1t, fw2t, pb);
    conv12_kernel<<<1024, 256, 0, stream>>>(x, w1b, b1, w2b, b2, pb, p2b);
    conv3_mfma<<<256, 256, 0, stream>>>(p2b, w3b, b3, pb, h3);
    fc_kernel<<<1024, 128, 0, stream>>>(h3, fw1t, fb1, fw2t, fb2, pb, out);
}

// Round 15
// 161.230 us; speedup vs baseline: 2.0111x; 2.0111x over previous
//
#include <hip/hip_runtime.h>
#include <hip/hip_bf16.h>
#include <math.h>

// ---------------------------------------------------------------------------
// TernaryLeNet5 forward.
// R14: RESTORE R12-exact (best verified: 162.1us). R13 (cooperative launch)
// failed under the harness capture path; R14's sync-free redundant-delta
// ternarize was 208-270us (750 serial scalar loads/thread at 80 blocks,
// zero pipelining — redundant compute is only free when latency-tolerant).
// Structure: tern_pass1 + tern_pass2 (16 blk/tensor), conv12 (4-chunk
// im2col MFMA, stride-36 A, 4 blocks/CU), conv3_mfma (256 blk), fc (1024).
// Cross-session drift ~15% on identical code — compare within-run only.
// Known: harness's ~40us ws-poison fill is inside dur_us (uncontrollable).
// ---------------------------------------------------------------------------

typedef __attribute__((ext_vector_type(8))) short bf16x8;
typedef __attribute__((ext_vector_type(4))) float f32x4;

// ---- ws layout (float offsets) --------------------------------------------
// pb: pabs[5][16] @0, ps1[5][16] @80, pcnt[5][16] @160
static const size_t OFF_PB    = 0;        // 240 f32
static const size_t OFF_W1B   = 256;      // [32][32] bf16 = 512 f32
static const size_t OFF_W2B   = 1056;     // [64][25][32] bf16 = 25600 f32
static const size_t OFF_W3B   = 26656;    // [128][1600] bf16  = 102400 f32
static const size_t OFF_FW1T  = 129056;   // [120][84] f32, +-1/0
static const size_t OFF_FW2T  = 139136;   // [84][10] f32, +-1/0
static const size_t OFF_P2B   = 139976;   // [1024][1600] bf16 = 819200 f32
static const size_t OFF_H3    = 959176;   // [1024][120] f32
// total ~4.3 MB

#define BPT 16   // blocks per tensor in ternarize passes

__device__ __forceinline__ ushort f2bf(float v) {   // RNE float->bf16 bits
    unsigned u = __float_as_uint(v);
    unsigned r = (u + 0x7FFFu + ((u >> 16) & 1u)) >> 16;
    return (ushort)r;
}
__device__ __forceinline__ float bf2f(ushort h) {
    return __uint_as_float((unsigned)h << 16);
}

// tanh via hw exp: 1 - 2e/(1+e), e = exp(-2|x|) in (0,1] -> no overflow.
__device__ __forceinline__ float tanh_fast(float x) {
    float e = __expf(-2.0f * fabsf(x));
    float r = 1.0f - 2.0f * e / (1.0f + e);
    return copysignf(r, x);
}

__device__ __forceinline__ void tensor_select(int tensor,
        const float* w1, const float* w2, const float* w3,
        const float* fw1, const float* fw2,
        const float*& src, int& O, int& K) {
    switch (tensor) {
        case 0: src = w1;  O = 32;  K = 25;   break;
        case 1: src = w2;  O = 64;  K = 800;  break;
        case 2: src = w3;  O = 120; K = 1600; break;
        case 3: src = fw1; O = 84;  K = 120;  break;
        default: src = fw2; O = 10; K = 84;   break;
    }
}

__device__ __forceinline__ float block_sum_256(float v, float* sbuf) {
    #pragma unroll
    for (int off = 32; off > 0; off >>= 1) v += __shfl_down(v, off);
    const int wid = threadIdx.x >> 6;
    if ((threadIdx.x & 63) == 0) sbuf[wid] = v;
    __syncthreads();
    return sbuf[0] + sbuf[1] + sbuf[2] + sbuf[3];
}

// alpha for `tensor` from pass2 partials (redundant per-thread compute)
__device__ __forceinline__ float alpha_of(const float* pb, int tensor) {
    float s1 = 0.f, c = 0.f;
    #pragma unroll
    for (int i = 0; i < BPT; ++i) {
        s1 += pb[80 + tensor * BPT + i];
        c  += pb[160 + tensor * BPT + i];
    }
    return s1 / fmaxf(c, 1.0f);
}

// ---------------------------------------------------------------------------
__global__ __launch_bounds__(256)
void tern_pass1(const float* w1, const float* w2, const float* w3,
                const float* fw1, const float* fw2, float* pb) {
    __shared__ float sbuf[4];
    const int tensor = blockIdx.x / BPT;
    const int blk    = blockIdx.x % BPT;
    const float* src; int O, K;
    tensor_select(tensor, w1, w2, w3, fw1, fw2, src, O, K);
    const int n = O * K;
    float s = 0.f;
    for (int i = blk * 256 + threadIdx.x; i < n; i += BPT * 256)
        s += fabsf(src[i]);
    s = block_sum_256(s, sbuf);
    if (threadIdx.x == 0) pb[tensor * BPT + blk] = s;
}

// pass2: delta from pass1 partials; quantize to +-1/0; write masked partials.
__global__ __launch_bounds__(256)
void tern_pass2(const float* w1, const float* w2, const float* w3,
                const float* fw1, const float* fw2,
                ushort* w1b, ushort* w2b, ushort* w3b,
                float* fw1t, float* fw2t, float* pb) {
    __shared__ float sbuf[4];
    const int tensor = blockIdx.x / BPT;
    const int blk    = blockIdx.x % BPT;
    const float* src; int O, K;
    tensor_select(tensor, w1, w2, w3, fw1, fw2, src, O, K);
    const int n = O * K;
    float tot = 0.f;
    #pragma unroll
    for (int i = 0; i < BPT; ++i) tot += pb[tensor * BPT + i];
    const float delta = 0.7f * tot / (float)n;

    const ushort BP = 0x3F80u, BN = 0xBF80u;   // bf16 +1, -1
    float s1 = 0.f, cnt = 0.f;

    if (tensor == 0) {
        // w1 -> bf16 [oc][32]: k 0..24 = taps, k 25..31 = 0 (pads MFMA K)
        for (int j = blk * 256 + threadIdx.x; j < 1024; j += BPT * 256) {
            const int oc = j >> 5, kk = j & 31;
            ushort qb = 0;
            if (kk < 25) {
                float w = src[oc * 25 + kk];
                float aw = fabsf(w);
                if (aw > delta) { s1 += aw; cnt += 1.f; qb = (w > 0.f) ? BP : BN; }
            }
            w1b[j] = qb;
        }
    } else if (tensor == 2) {
        // w3 -> bf16 [oc][1600] row-linear; zero-fill pad rows 120..127
        for (int i = blk * 256 + threadIdx.x; i < 128 * 1600; i += BPT * 256) {
            ushort qb = 0;
            if (i < n) {
                float w = src[i];
                float aw = fabsf(w);
                if (aw > delta) { s1 += aw; cnt += 1.f; qb = (w > 0.f) ? BP : BN; }
            }
            w3b[i] = qb;
        }
    } else if (tensor == 1) {
        // w2 -> bf16 [oc][tap][ic]; src is [oc][ic][kh][kw]
        for (int i = blk * 256 + threadIdx.x; i < n; i += BPT * 256) {
            float w = src[i];
            float aw = fabsf(w);
            ushort qb = 0;
            if (aw > delta) { s1 += aw; cnt += 1.f; qb = (w > 0.f) ? BP : BN; }
            int oc = i / 800;
            int r  = i - oc * 800;
            int ic = r / 25;
            int tap = r - ic * 25;
            w2b[oc * 800 + tap * 32 + ic] = qb;
        }
    } else {
        float* dst = (tensor == 3) ? fw1t : fw2t;
        for (int i = blk * 256 + threadIdx.x; i < n; i += BPT * 256) {
            float w = src[i];
            float aw = fabsf(w);
            float q = 0.f;
            if (aw > delta) { s1 += aw; cnt += 1.f; q = (w > 0.f) ? 1.f : -1.f; }
            int o = i / K;
            int k = i - o * K;
            dst[k * O + o] = q;      // transpose to [k][O]
        }
    }
    s1 = block_sum_256(s1, sbuf);
    __syncthreads();
    cnt = block_sum_256(cnt, sbuf);
    if (threadIdx.x == 0) {
        pb[80 + tensor * BPT + blk]  = s1;
        pb[160 + tensor * BPT + blk] = cnt;
    }
}

// ---------------------------------------------------------------------------
// conv2 MFMA inner (stride 40 sxt)
template<int TBASE, int TCNT>
__device__ __forceinline__ void conv2_phase(
        const ushort* __restrict__ w2b, const ushort* sxt,
        int n0, int mt0, int lane, f32x4 acc[4][2]) {
    const int col = lane & 15, quad = lane >> 4;
    bf16x8 bfr[TCNT][2];
    #pragma unroll
    for (int i = 0; i < TCNT; ++i) {
        const int tap = TBASE + i;
        #pragma unroll
        for (int np = 0; np < 2; ++np) {
            const int oc = n0 + np * 16 + col;
            bfr[i][np] = *(const bf16x8*)(w2b + (oc * 25 + tap) * 32 + quad * 8);
        }
    }
    #pragma unroll
    for (int mi = 0; mi < 4; ++mi) {
        int m = (mt0 + mi) * 16 + col;
        m = m < 100 ? m : 99;                     // clamp padding rows
        const int oh = m / 10, ow = m - oh * 10;
        const ushort* abase = sxt + (oh * 14 + ow) * 40 + quad * 8;
        #pragma unroll
        for (int i = 0; i < TCNT; ++i) {
            const int tap = TBASE + i;
            const int kh = tap / 5, kw = tap - kh * 5;
            bf16x8 af = *(const bf16x8*)(abase + (kh * 14 + kw) * 40);
            acc[mi][0] = __builtin_amdgcn_mfma_f32_16x16x32_bf16(af, bfr[i][0], acc[mi][0], 0, 0, 0);
            acc[mi][1] = __builtin_amdgcn_mfma_f32_16x16x32_bf16(af, bfr[i][1], acc[mi][1], 0, 0, 0);
        }
    }
}

// ---------------------------------------------------------------------------
// conv12: conv1 MFMA (4-chunk im2col, conflict-free stride-36 A) + pool +
// conv2 MFMA + pool. One image per block, 4 blocks/CU.
__global__ __launch_bounds__(256)
void conv12_kernel(const float* __restrict__ x, const ushort* __restrict__ w1b,
                   const float* __restrict__ b1, const ushort* __restrict__ w2b,
                   const float* __restrict__ b2, const float* __restrict__ pb,
                   ushort* __restrict__ p2b) {
    __shared__ __align__(16) char smem[40776];
    ushort* A      = (ushort*)smem;
    ushort* sxt    = (ushort*)smem;
    ushort* hb1    = (ushort*)(smem + 15680);
    float*  hb2    = (float*) (smem + 15680);
    ushort* sxb    = (ushort*)(smem + 38720);
    float*  salpha = (float*) (smem + 40768);

    const int n = blockIdx.x;
    const int t = threadIdx.x;
    const int wave = t >> 6, lane = t & 63;
    const int col = lane & 15, quad = lane >> 4;

    bf16x8 B0 = *(const bf16x8*)(w1b + col * 32 + quad * 8);
    bf16x8 B1 = *(const bf16x8*)(w1b + (col + 16) * 32 + quad * 8);
    const float b1reg = b1[t & 31];

    {   // stage x -> bf16 sxb
        float4 v = ((const float4*)(x + (size_t)n * 1024))[t];
        ushort4 q;
        q.x = f2bf(v.x); q.y = f2bf(v.y); q.z = f2bf(v.z); q.w = f2bf(v.w);
        *(ushort4*)(sxb + t * 4) = q;
        if (t == 0) salpha[0] = alpha_of(pb, 0);
        if (t == 1) salpha[1] = alpha_of(pb, 1);
    }
    __syncthreads();

    // ---- conv1: 4 chunks of tiles {13,13,13,10} -------------------------
    #pragma unroll
    for (int c = 0; c < 4; ++c) {
        const int tbase = c * 13;
        const int ct    = (c == 3) ? 10 : 13;
        const int pbase = tbase * 16;
        const int rows  = ct * 16;

        for (int r = t; r < rows; r += 256) {
            const int p = pbase + r;
            const int oh = p / 28, ow = p % 28;
            ushort v[25];
            #pragma unroll
            for (int kh = 0; kh < 5; ++kh) {
                const ushort* rr = sxb + (oh + kh) * 32 + ow;
                v[kh*5+0]=rr[0]; v[kh*5+1]=rr[1]; v[kh*5+2]=rr[2];
                v[kh*5+3]=rr[3]; v[kh*5+4]=rr[4];
            }
            uint2* arow = (uint2*)(A + r * 36);   // 72B rows: banks 18r%32
            #pragma unroll
            for (int j = 0; j < 6; ++j) {
                uint2 w;
                w.x = (unsigned)v[4*j]   | ((unsigned)v[4*j+1] << 16);
                w.y = (unsigned)v[4*j+2] | ((unsigned)v[4*j+3] << 16);
                arow[j] = w;
            }
            uint2 w6; w6.x = (unsigned)v[24]; w6.y = 0u;
            arow[6] = w6;
            uint2 w7; w7.x = 0u; w7.y = 0u;
            arow[7] = w7;
        }
        __syncthreads();

        for (int tl = wave; tl < ct; tl += 4) {
            const ushort* ap = A + (tl * 16 + col) * 36 + quad * 8;
            ushort4 lo = *(const ushort4*)ap;
            ushort4 hi = *(const ushort4*)(ap + 4);
            bf16x8 af;
            af[0]=(short)lo.x; af[1]=(short)lo.y; af[2]=(short)lo.z; af[3]=(short)lo.w;
            af[4]=(short)hi.x; af[5]=(short)hi.y; af[6]=(short)hi.z; af[7]=(short)hi.w;
            f32x4 z = {};
            f32x4 c0 = __builtin_amdgcn_mfma_f32_16x16x32_bf16(af, B0, z, 0, 0, 0);
            f32x4 c1 = __builtin_amdgcn_mfma_f32_16x16x32_bf16(af, B1, z, 0, 0, 0);
            const int p = pbase + tl * 16 + quad * 4;
            const int oh = p / 28, ow2 = (p % 28) >> 1;
            const int pos = oh * 14 + ow2;
            hb1[pos * 32 + col]            = f2bf(fmaxf(c0[0], c0[1]));
            hb1[(pos + 1) * 32 + col]      = f2bf(fmaxf(c0[2], c0[3]));
            hb1[pos * 32 + col + 16]       = f2bf(fmaxf(c1[0], c1[1]));
            hb1[(pos + 1) * 32 + col + 16] = f2bf(fmaxf(c1[2], c1[3]));
        }
        __syncthreads();
    }

    // ---- vertical pool + alpha/bias + tanh -> sxt (overlays A) ----------
    {
        const float a1 = salpha[0];
        const int oc = t & 31;
        for (int idx = t; idx < 6272; idx += 256) {
            const int pos2 = idx >> 5;
            const int ph = pos2 / 14, pw = pos2 - ph * 14;
            const int in0 = (2 * ph) * 14 + pw;
            float m = fmaxf(bf2f(hb1[in0 * 32 + oc]),
                            bf2f(hb1[(in0 + 14) * 32 + oc]));
            sxt[pos2 * 40 + oc] = f2bf(tanh_fast(fmaf(a1, m, b1reg)));
        }
    }
    __syncthreads();

    // ---- conv2 MFMA -----------------------------------------------------
    const int n0  = (wave & 1) * 32;
    const int mt0 = (wave >> 1) * 4;
    f32x4 acc2[4][2] = {};
    conv2_phase<0, 13>(w2b, sxt, n0, mt0, lane, acc2);
    conv2_phase<13, 12>(w2b, sxt, n0, mt0, lane, acc2);

    {   // horizontal pool in-register -> hb2[oc][50]
        #pragma unroll
        for (int mi = 0; mi < 4; ++mi) {
            const int mrow = (mt0 + mi) * 16 + quad * 4;
            if (mrow < 100) {
                #pragma unroll
                for (int np = 0; np < 2; ++np) {
                    const int oc = n0 + np * 16 + col;
                    float2 hm;
                    hm.x = fmaxf(acc2[mi][np][0], acc2[mi][np][1]);
                    hm.y = fmaxf(acc2[mi][np][2], acc2[mi][np][3]);
                    *(float2*)(&hb2[oc * 50 + (mrow >> 1)]) = hm;
                }
            }
        }
    }
    __syncthreads();

    const float a2 = salpha[1];
    for (int idx = t; idx < 1600; idx += 256) {
        const int oc = idx / 25, r = idx - oc * 25;
        const int ph = r / 5, pw = r - ph * 5;
        const float* hb = &hb2[oc * 50 + ph * 10 + pw];
        float m = fmaxf(hb[0], hb[5]);
        p2b[(size_t)n * 1600 + idx] = f2bf(tanh_fast(fmaf(a2, m, b2[oc])));
    }
}

// ---------------------------------------------------------------------------
// conv3 as MFMA GEMM: h3[1024][120] = tanh(a3*(P2 x W3^T) + b3)
template<int STEPS>
__device__ __forceinline__ void conv3_chunk(const ushort* Abase, const ushort* B0,
                                            const ushort* B1, f32x4& acc0, f32x4& acc1) {
    #pragma unroll
    for (int s = 0; s < STEPS; ++s) {
        bf16x8 af = *(const bf16x8*)(Abase + s * 32);
        bf16x8 b0 = *(const bf16x8*)(B0 + s * 32);
        bf16x8 b1 = *(const bf16x8*)(B1 + s * 32);
        acc0 = __builtin_amdgcn_mfma_f32_16x16x32_bf16(af, b0, acc0, 0, 0, 0);
        acc1 = __builtin_amdgcn_mfma_f32_16x16x32_bf16(af, b1, acc1, 0, 0, 0);
    }
}

__global__ __launch_bounds__(256)
void conv3_mfma(const ushort* __restrict__ p2b, const ushort* __restrict__ w3b,
                const float* __restrict__ b3, const float* __restrict__ pb,
                float* __restrict__ h3) {
    __shared__ float red[4][64][8];   // [wave][lane][np*4+reg]
    __shared__ float salpha;
    const int t = threadIdx.x;
    const int wave = t >> 6, lane = t & 63;
    const int mt = blockIdx.x >> 2;       // 0..63
    const int npair = blockIdx.x & 3;     // 0..3
    const int col = lane & 15, quad = lane >> 4;
    const int kstart = (wave < 2) ? wave * 13 : 26 + (wave - 2) * 12;  // 0,13,26,38

    if (t == 0) salpha = alpha_of(pb, 2);

    const ushort* Abase = p2b + (size_t)(mt * 16 + col) * 1600 + kstart * 32 + quad * 8;
    const ushort* B0 = w3b + (size_t)(npair * 32 + col) * 1600 + kstart * 32 + quad * 8;
    const ushort* B1 = B0 + 16 * 1600;

    f32x4 acc0 = {}, acc1 = {};
    if (wave < 2) conv3_chunk<13>(Abase, B0, B1, acc0, acc1);
    else          conv3_chunk<12>(Abase, B0, B1, acc0, acc1);

    #pragma unroll
    for (int r = 0; r < 4; ++r) {
        red[wave][lane][r]     = acc0[r];
        red[wave][lane][4 + r] = acc1[r];
    }
    __syncthreads();

    {   // thread t: lane l = t&63, reg vh = t>>6; handles np = 0 and 1
        const float a3 = salpha;
        const int l = t & 63, vh = t >> 6;
        const int lcol = l & 15, lquad = l >> 4;
        const int img = mt * 16 + lquad * 4 + vh;
        #pragma unroll
        for (int j = 0; j < 2; ++j) {
            const int v = j * 4 + vh;
            float s = red[0][l][v] + red[1][l][v] + red[2][l][v] + red[3][l][v];
            const int oc = npair * 32 + j * 16 + lcol;
            if (oc < 120) h3[(size_t)img * 120 + oc] = tanh_fast(fmaf(a3, s, b3[oc]));
        }
    }
}

// ---------------------------------------------------------------------------
// fc1 + tanh + fc2 + softmax. Block per image; alpha folded.
__global__ __launch_bounds__(128)
void fc_kernel(const float* __restrict__ h3, const float* __restrict__ fw1t,
               const float* __restrict__ fb1, const float* __restrict__ fw2t,
               const float* __restrict__ fb2, const float* __restrict__ pb,
               float* __restrict__ out) {
    const int n = blockIdx.x;
    __shared__ float sh[120];
    __shared__ float sh4[84];
    __shared__ float sl[10];
    __shared__ float salpha[2];
    const int t = threadIdx.x;
    if (t < 120) sh[t] = h3[(size_t)n * 120 + t];
    if (t == 120) salpha[0] = alpha_of(pb, 3);
    if (t == 121) salpha[1] = alpha_of(pb, 4);
    __syncthreads();
    if (t < 84) {
        const float af1 = salpha[0];
        float a = 0.f;
        #pragma unroll 4
        for (int k = 0; k < 120; ++k) a = fmaf(fw1t[k * 84 + t], sh[k], a);
        sh4[t] = tanh_fast(fmaf(af1, a, fb1[t]));
    }
    __syncthreads();
    if (t < 10) {
        const float af2 = salpha[1];
        float a = 0.f;
        #pragma unroll 4
        for (int k = 0; k < 84; ++k) a = fmaf(fw2t[k * 10 + t], sh4[k], a);
        const float lg = fmaf(af2, a, fb2[t]);
        sl[t] = lg;
        out[(size_t)n * 10 + t] = lg;
    }
    __syncthreads();
    if (t < 10) {
        float m = -INFINITY;
        #pragma unroll
        for (int i = 0; i < 10; ++i) m = fmaxf(m, sl[i]);
        float s = 0.f;
        #pragma unroll
        for (int i = 0; i < 10; ++i) s += expf(sl[i] - m);
        out[10240 + (size_t)n * 10 + t] = expf(sl[t] - m) / s;
    }
}

// ---------------------------------------------------------------------------
extern "C" void kernel_launch(void* const* d_in, const int* in_sizes, int n_in,
                              void* d_out, int out_size, void* d_ws, size_t ws_size,
                              hipStream_t stream) {
    const float* x   = (const float*)d_in[0];
    const float* w1  = (const float*)d_in[1];
    const float* b1  = (const float*)d_in[2];
    const float* w2  = (const float*)d_in[3];
    const float* b2  = (const float*)d_in[4];
    const float* w3  = (const float*)d_in[5];
    const float* b3  = (const float*)d_in[6];
    const float* fw1 = (const float*)d_in[7];
    const float* fb1 = (const float*)d_in[8];
    const float* fw2 = (const float*)d_in[9];
    const float* fb2 = (const float*)d_in[10];

    float* ws = (float*)d_ws;
    float*  pb   = ws + OFF_PB;
    ushort* w1b  = (ushort*)(ws + OFF_W1B);
    ushort* w2b  = (ushort*)(ws + OFF_W2B);
    ushort* w3b  = (ushort*)(ws + OFF_W3B);
    float*  fw1t = ws + OFF_FW1T;
    float*  fw2t = ws + OFF_FW2T;
    ushort* p2b  = (ushort*)(ws + OFF_P2B);
    float*  h3   = ws + OFF_H3;
    float*  out  = (float*)d_out;

    tern_pass1<<<5 * BPT, 256, 0, stream>>>(w1, w2, w3, fw1, fw2, pb);
    tern_pass2<<<5 * BPT, 256, 0, stream>>>(w1, w2, w3, fw1, fw2,
                                            w1b, w2b, w3b, fw1t, fw2t, pb);
    conv12_kernel<<<1024, 256, 0, stream>>>(x, w1b, b1, w2b, b2, pb, p2b);
    conv3_mfma<<<256, 256, 0, stream>>>(p2b, w3b, b3, pb, h3);
    fc_kernel<<<1024, 128, 0, stream>>>(h3, fw1t, fb1, fw2t, fb2, pb, out);
}